// Round 4
// baseline (81037.915 us; speedup 1.0000x reference)
//
#include <hip/hip_runtime.h>

// CascadedAttention: B=32, T=1024, D=1024, O=256. All I/O f32.
// ws (33.55 MB, proven): E[b][t][o] = exp(2*(in@Ua+Ba2)) bf16 (16.78 MB)
//                        IC[b][t][o] = in@Co bf16 (16.78 MB)
// UoHp staged in d_out rows (f32), consumed at step t, replaced by pred.
// Scan: 256 blocks x 512 thr; b=blk&31, g=blk>>5 (8 blocks/b on SAME XCD).
//   block g: scores for t' in [128g,128g+128) (needs full F), output o-chunk
//   [32g,32g+32). Exchange via __device__ globals + 2 flag barriers/step.

typedef unsigned int uint32;
typedef unsigned short u16;

#define GG 8
#define NTH 512

__device__ __forceinline__ float b2f(u16 u) { return __uint_as_float(((uint32)u) << 16); }
__device__ __forceinline__ u16 f2b(float f) {
    uint32 u = __float_as_uint(f);
    uint32 r = u + 0x7fffu + ((u >> 16) & 1u);
    return (u16)(r >> 16);
}
__device__ __forceinline__ float lo_bf(uint32 d) { return __uint_as_float(d << 16); }
__device__ __forceinline__ float hi_bf(uint32 d) { return __uint_as_float(d & 0xffff0000u); }
__device__ __forceinline__ float tanh_fast(float x) {
    float e = __expf(x + x);
    return 1.0f - 2.0f * __builtin_amdgcn_rcpf(e + 1.0f);
}

#define OFF_E  ((size_t)0)
#define OFF_IC ((size_t)16777216)
#define WS_NEEDED ((size_t)33554432)

// ---------------- exchange state (device globals; re-zeroed every launch) ----
__device__ float g_embWo[256];
__device__ float g_pred[32 * 256];
__device__ float g_part[32 * 8 * 256];
__device__ float g_scores[32 * 1024];
__device__ int g_flagA[32 * 1024];
__device__ int g_flagB[32 * 1024];

__global__ __launch_bounds__(256) void init_k() {
    int i = blockIdx.x * 256 + threadIdx.x;      // grid 256 -> i in [0,65536)
    if (i < 32 * 256) g_pred[i] = 0.f;
    if (i < 32 * 8 * 256) g_part[i] = 0.f;
    if (i < 32 * 1024) { g_flagA[i] = 0; g_flagB[i] = 0; }
}

__global__ void setup_embWo(const float* __restrict__ emb, const float* __restrict__ Wo) {
    int o = threadIdx.x;
    float a = 0.f;
    for (int j = 0; j < 256; j++) a = fmaf(emb[o * 256 + j], Wo[j], a);
    g_embWo[o] = a;
}

// ---------------- K1: fused precompute GEMM (f32 in) ----------------
__global__ __launch_bounds__(256) void gemm_pre(
    const float* __restrict__ in, const float* __restrict__ Ua,
    const float* __restrict__ Uo, const float* __restrict__ Co,
    const float* __restrict__ Ba2, const float* __restrict__ Bo2,
    const float* __restrict__ Bo3, const float* __restrict__ Bo4,
    u16* __restrict__ E, float* __restrict__ outStage, u16* __restrict__ ic) {
    __shared__ __align__(16) float smA[32][132];
    __shared__ __align__(16) float smB[32][128];

    int tid = threadIdx.x;
    int rt = blockIdx.x, ct = blockIdx.y;
    int mat = ct >> 1;
    int o0 = (ct & 1) * 128;
    const float* W = (mat == 0) ? Ua : (mat == 1 ? Uo : Co);
    int r0 = rt * 128;
    int b = r0 >> 10, t0 = r0 & 1023;
    int tr = tid >> 4, tc = tid & 15;

    float acc[8][8];
#pragma unroll
    for (int i = 0; i < 8; i++)
#pragma unroll
        for (int j = 0; j < 8; j++) acc[i][j] = 0.f;

    for (int kc = 0; kc < 1024; kc += 32) {
#pragma unroll
        for (int l = 0; l < 4; l++) {
            int s = tid + l * 256;
            int i = s >> 3, c = s & 7;
            float4 v = *(const float4*)(in + (size_t)(r0 + i) * 1024 + kc + c * 4);
            smA[c * 4 + 0][i] = v.x;
            smA[c * 4 + 1][i] = v.y;
            smA[c * 4 + 2][i] = v.z;
            smA[c * 4 + 3][i] = v.w;
        }
#pragma unroll
        for (int l = 0; l < 4; l++) {
            int s = tid + l * 256;
            int dd = s >> 5, c = s & 31;
            *(float4*)&smB[dd][c * 4] = *(const float4*)(W + (size_t)(kc + dd) * 256 + o0 + c * 4);
        }
        __syncthreads();
#pragma unroll 4
        for (int j = 0; j < 32; j++) {
            float a0[8], b0[8];
            *(float4*)&a0[0] = *(const float4*)&smA[j][tr * 8];
            *(float4*)&a0[4] = *(const float4*)&smA[j][tr * 8 + 4];
            *(float4*)&b0[0] = *(const float4*)&smB[j][tc * 8];
            *(float4*)&b0[4] = *(const float4*)&smB[j][tc * 8 + 4];
#pragma unroll
            for (int rr = 0; rr < 8; rr++)
#pragma unroll
                for (int cc = 0; cc < 8; cc++) acc[rr][cc] = fmaf(a0[rr], b0[cc], acc[rr][cc]);
        }
        __syncthreads();
    }

    if (mat == 0) {
#pragma unroll
        for (int rr = 0; rr < 8; rr++) {
            int t = t0 + tr * 8 + rr;
#pragma unroll
            for (int cc = 0; cc < 8; cc++) {
                int o = o0 + tc * 8 + cc;
                float v = __expf(2.f * (acc[rr][cc] + Ba2[t * 256 + o]));
                E[((((size_t)b << 10) + t) << 8) + o] = f2b(v);   // [b][t][o]
            }
        }
    } else if (mat == 1) {
#pragma unroll
        for (int rr = 0; rr < 8; rr++) {
            int t = t0 + tr * 8 + rr;
            int t1 = (t + 1) & 1023;
#pragma unroll
            for (int cc = 0; cc < 8; cc++) {
                int o = o0 + tc * 8 + cc;
                outStage[(((size_t)b << 10) + t1) * 256 + o] = acc[rr][cc] + Bo2[o] + Bo3[o] + Bo4[o];
            }
        }
    } else {
#pragma unroll
        for (int rr = 0; rr < 8; rr++) {
            int t = t0 + tr * 8 + rr;
#pragma unroll
            for (int cc = 0; cc < 8; cc++)
                ic[(((size_t)b << 10) + t) * 256 + o0 + tc * 8 + cc] = f2b(acc[rr][cc]);
        }
    }
}

// ---------------- K2: scan, 8 blocks/b x 512 thr ----------------
__global__ __launch_bounds__(NTH) void seq8(
    const float* __restrict__ Wa, const float* __restrict__ Va,
    const float* __restrict__ Ba1, const float* __restrict__ Ba3,
    const u16* __restrict__ E, const u16* __restrict__ IC,
    float* __restrict__ out) {
    __shared__ float smVa[256], smBa1[256], smF[256], smBa3[128];
    __shared__ float smW[1024];
    __shared__ float smQ[32];
    __shared__ __align__(16) float smRed[1024];
    __shared__ float smT[16];

    int tid = threadIdx.x;
    int b = blockIdx.x & 31, g = blockIdx.x >> 5;
    int lane = tid & 63, w = tid >> 6;

    if (tid < 256) { smVa[tid] = Va[tid]; smBa1[tid] = Ba1[tid]; }
    if (tid < 128) smBa3[tid] = Ba3[(g << 7) + tid];
    __syncthreads();

    float sv = (tid < 256) ? smVa[tid] : 0.f;
#pragma unroll
    for (int off = 32; off; off >>= 1) sv += __shfl_xor(sv, off, 64);
    if (lane == 0) smT[w] = sv;
    __syncthreads();
    float sumVa = 0.f;
#pragma unroll
    for (int i = 0; i < 8; i++) sumVa += smT[i];
    __syncthreads();

    float myEmb = (tid < 256) ? g_embWo[tid] : 0.f;

    // Wa rows [32g, 32g+32) column tid, bf16-packed (used for next-step WaS partial)
    uint32 WaP[16];
    if (tid < 256) {
#pragma unroll 4
        for (int k2 = 0; k2 < 16; k2++) {
            int row = (g << 5) + 2 * k2;
            uint32 u0 = (uint32)f2b(Wa[(size_t)row * 256 + tid]);
            uint32 u1 = (uint32)f2b(Wa[(size_t)(row + 1) * 256 + tid]);
            WaP[k2] = u0 | (u1 << 16);
        }
    }

    float* outb = out + ((size_t)b << 18);

    for (int t = 0; t < 1024; t++) {
        int fb = (b << 10) + t;
        if (t > 0) {
            if (tid == 0) {
                int bud = 100000000;
                while (__hip_atomic_load(&g_flagB[fb - 1], __ATOMIC_RELAXED, __HIP_MEMORY_SCOPE_AGENT) < GG && --bud) {}
                (void)__hip_atomic_load(&g_flagB[fb - 1], __ATOMIC_ACQUIRE, __HIP_MEMORY_SCOPE_AGENT);
            }
            __syncthreads();
        }
        // ---- pre: p_val pieces + F from WaS partials (tid<256) ----
        float pv = 0.f;
        if (tid < 256) {
            pv = g_pred[(b << 8) + tid];
            float m = pv;
#pragma unroll
            for (int off = 32; off; off >>= 1) m = fmaxf(m, __shfl_xor(m, off, 64));
            if (lane == 0) smT[w] = m;
        }
        __syncthreads();
        if (tid < 256) {
            float M = fmaxf(fmaxf(smT[0], smT[1]), fmaxf(smT[2], smT[3]));
            float e = __expf(pv - M);
            float s1 = e, s2 = e * myEmb;
#pragma unroll
            for (int off = 32; off; off >>= 1) {
                s1 += __shfl_xor(s1, off, 64);
                s2 += __shfl_xor(s2, off, 64);
            }
            if (lane == 0) { smT[4 + w] = s1; smT[8 + w] = s2; }
            float was = smBa1[tid];
            const float* pp = &g_part[(b << 3) * 256 + tid];
#pragma unroll
            for (int g2 = 0; g2 < 8; g2++) was += pp[g2 << 8];
            smF[tid] = __expf(2.f * was);
        }
        __syncthreads();
        float p_val = (smT[8] + smT[9] + smT[10] + smT[11]) *
                      __builtin_amdgcn_rcpf(smT[4] + smT[5] + smT[6] + smT[7]);

        // ---- phase C: scores for t' slice [128g,128g+128), 4 thr/row ----
        {
            int tl = tid >> 2, oq = tid & 3;
            int tp = (g << 7) + tl;
            const uint4* row = (const uint4*)(E + ((((size_t)b << 10) + tp) << 8) + (oq << 6));
            float acc = 0.f;
#pragma unroll
            for (int k = 0; k < 8; k++) {
                uint4 ev = row[k];
                int ob = (oq << 6) + (k << 3);
                float4 fA = *(const float4*)&smF[ob];
                float4 fB = *(const float4*)&smF[ob + 4];
                float4 vA = *(const float4*)&smVa[ob];
                float4 vB = *(const float4*)&smVa[ob + 4];
                acc = fmaf(vA.x, __builtin_amdgcn_rcpf(fmaf(lo_bf(ev.x), fA.x, 1.f)), acc);
                acc = fmaf(vA.y, __builtin_amdgcn_rcpf(fmaf(hi_bf(ev.x), fA.y, 1.f)), acc);
                acc = fmaf(vA.z, __builtin_amdgcn_rcpf(fmaf(lo_bf(ev.y), fA.z, 1.f)), acc);
                acc = fmaf(vA.w, __builtin_amdgcn_rcpf(fmaf(hi_bf(ev.y), fA.w, 1.f)), acc);
                acc = fmaf(vB.x, __builtin_amdgcn_rcpf(fmaf(lo_bf(ev.z), fB.x, 1.f)), acc);
                acc = fmaf(vB.y, __builtin_amdgcn_rcpf(fmaf(hi_bf(ev.z), fB.y, 1.f)), acc);
                acc = fmaf(vB.z, __builtin_amdgcn_rcpf(fmaf(lo_bf(ev.w), fB.z, 1.f)), acc);
                acc = fmaf(vB.w, __builtin_amdgcn_rcpf(fmaf(hi_bf(ev.w), fB.w, 1.f)), acc);
            }
            acc += __shfl_xor(acc, 1, 64);
            acc += __shfl_xor(acc, 2, 64);
            if (oq == 0) g_scores[(b << 10) + tp] = sumVa - 2.f * acc + smBa3[tl];
        }
        __threadfence();
        __syncthreads();
        if (tid == 0) {
            __hip_atomic_fetch_add(&g_flagA[fb], 1, __ATOMIC_RELEASE, __HIP_MEMORY_SCOPE_AGENT);
            int bud = 100000000;
            while (__hip_atomic_load(&g_flagA[fb], __ATOMIC_RELAXED, __HIP_MEMORY_SCOPE_AGENT) < GG && --bud) {}
            (void)__hip_atomic_load(&g_flagA[fb], __ATOMIC_ACQUIRE, __HIP_MEMORY_SCOPE_AGENT);
        }
        __syncthreads();

        // ---- softmax over all 1024 scores (redundant per block) ----
        float s0 = g_scores[(b << 10) + tid];
        float s1_ = g_scores[(b << 10) + 512 + tid];
        float mm = fmaxf(s0, s1_);
#pragma unroll
        for (int off = 32; off; off >>= 1) mm = fmaxf(mm, __shfl_xor(mm, off, 64));
        if (lane == 0) smT[w] = mm;
        __syncthreads();
        float M2 = smT[0];
#pragma unroll
        for (int i = 1; i < 8; i++) M2 = fmaxf(M2, smT[i]);
        float e0 = __expf(s0 - M2), e1 = __expf(s1_ - M2);
        smW[tid] = e0;
        smW[512 + tid] = e1;
        float ls = e0 + e1;
#pragma unroll
        for (int off = 32; off; off >>= 1) ls += __shfl_xor(ls, off, 64);
        if (lane == 0) smT[8 + w] = ls;
        __syncthreads();
        float L = 0.f;
#pragma unroll
        for (int i = 0; i < 8; i++) L += smT[8 + i];
        float invL = __builtin_amdgcn_rcpf(L);

        // ---- phase D: o-chunk [32g,32g+32), sum over all t' ----
        {
            int tc = tid >> 4, op = (tid & 15) << 1;
            const u16* icp = IC + ((((size_t)b << 10) + (tc << 5)) << 8) + (g << 5) + op;
            float a0 = 0.f, a1 = 0.f;
#pragma unroll 8
            for (int i = 0; i < 32; i++) {
                uint32 iv = *(const uint32*)(icp + ((size_t)i << 8));
                float wv = smW[(tc << 5) + i];
                a0 = fmaf(wv, lo_bf(iv), a0);
                a1 = fmaf(wv, hi_bf(iv), a1);
            }
            smRed[(tc << 5) + op] = a0;
            smRed[(tc << 5) + op + 1] = a1;
        }
        __syncthreads();
        if (tid < 32) {
            float s = 0.f;
#pragma unroll
            for (int c = 0; c < 32; c++) s += smRed[(c << 5) + tid];
            float uoh = outb[((size_t)t << 8) + (g << 5) + tid];
            float pr = p_val + uoh + invL * s;
            outb[((size_t)t << 8) + (g << 5) + tid] = pr;
            g_pred[(b << 8) + (g << 5) + tid] = pr;
            smQ[tid] = tanh_fast(pr);
        }
        __syncthreads();
        if (tid < 256) {
            float pa = 0.f;
#pragma unroll
            for (int k2 = 0; k2 < 16; k2++) {
                float2 q2 = *(const float2*)&smQ[k2 << 1];
                uint32 p = WaP[k2];
                pa = fmaf(lo_bf(p), q2.x, pa);
                pa = fmaf(hi_bf(p), q2.y, pa);
            }
            g_part[(((b << 3) + g) << 8) + tid] = pa;
        }
        __threadfence();
        __syncthreads();
        if (tid == 0)
            __hip_atomic_fetch_add(&g_flagB[fb], 1, __ATOMIC_RELEASE, __HIP_MEMORY_SCOPE_AGENT);
    }
}

// ---------------- fallback (ws too small): diagnostic zero-fill ----------------
__global__ void zero_k(uint32* out, int n) {
    int i = blockIdx.x * 1024 + threadIdx.x;
    if (i < n) out[i] = 0;
}

extern "C" void kernel_launch(void* const* d_in, const int* in_sizes, int n_in,
                              void* d_out, int out_size, void* d_ws, size_t ws_size,
                              hipStream_t stream) {
    const float* in = (const float*)d_in[0];
    const float* Wa = (const float*)d_in[1];
    const float* Ua = (const float*)d_in[2];
    const float* Va = (const float*)d_in[3];
    const float* Ba1 = (const float*)d_in[4];
    const float* Ba3 = (const float*)d_in[6];
    const float* Ba2 = (const float*)d_in[5];
    const float* Wo = (const float*)d_in[7];
    const float* Uo = (const float*)d_in[8];
    const float* Co = (const float*)d_in[9];
    const float* Bo2 = (const float*)d_in[10];
    const float* Bo3 = (const float*)d_in[11];
    const float* Bo4 = (const float*)d_in[12];
    const float* emb = (const float*)d_in[13];
    float* out = (float*)d_out;
    char* ws = (char*)d_ws;

    if (ws_size < WS_NEEDED) {
        zero_k<<<(out_size + 1023) / 1024, 1024, 0, stream>>>((uint32*)out, out_size);
        return;
    }

    u16* E = (u16*)(ws + OFF_E);
    u16* icp = (u16*)(ws + OFF_IC);

    init_k<<<256, 256, 0, stream>>>();
    setup_embWo<<<1, 256, 0, stream>>>(emb, Wo);
    gemm_pre<<<dim3(256, 6), 256, 0, stream>>>(in, Ua, Uo, Co, Ba2, Bo2, Bo3, Bo4, E, out, icp);
    seq8<<<256, NTH, 0, stream>>>(Wa, Va, Ba1, Ba3, E, icp, out);
}

// Round 5
// 10600.852 us; speedup vs baseline: 7.6445x; 7.6445x over previous
//
#include <hip/hip_runtime.h>

// CascadedAttention: B=32, T=1024, D=1024, O=256. All I/O f32.
// ws (33.55 MB): E[b][t][o]=exp(2*(in@Ua+Ba2)) bf16; IC[b][t][o]=in@Co bf16.
// UoHp staged in d_out (f32), consumed at step t, replaced by pred.
// Scan: 256 blocks x 512 thr; b=blk&31, g=blk>>5 (same-XCD heuristic only).
// ALL cross-block exchange via default-scope atomics (TCC-resident, device-
// coherent per m20) — no agent fences, no L2 shootdowns. Wa is LDS-resident
// (bf16-packed, 128KB) so WaS is computed in-block from atomically-read pred.

typedef unsigned int uint32;
typedef unsigned short u16;

#define GG 8
#define NTH 512

__device__ __forceinline__ float b2f(u16 u) { return __uint_as_float(((uint32)u) << 16); }
__device__ __forceinline__ u16 f2b(float f) {
    uint32 u = __float_as_uint(f);
    uint32 r = u + 0x7fffu + ((u >> 16) & 1u);
    return (u16)(r >> 16);
}
__device__ __forceinline__ float lo_bf(uint32 d) { return __uint_as_float(d << 16); }
__device__ __forceinline__ float hi_bf(uint32 d) { return __uint_as_float(d & 0xffff0000u); }
__device__ __forceinline__ float tanh_fast(float x) {
    float e = __expf(x + x);
    return 1.0f - 2.0f * __builtin_amdgcn_rcpf(e + 1.0f);
}

#define OFF_E  ((size_t)0)
#define OFF_IC ((size_t)16777216)
#define WS_NEEDED ((size_t)33554432)

// ---------------- exchange state (device globals; re-zeroed every launch) ----
__device__ float g_embWo[256];
__device__ float g_pred[32 * 256];
__device__ float g_scores[32 * 1024];
__device__ int g_flagA[32 * 1024];
__device__ int g_flagB[32 * 1024];

__global__ __launch_bounds__(256) void init_k() {
    int i = blockIdx.x * 256 + threadIdx.x;      // grid 256 -> i in [0,65536)
    if (i < 32 * 256) g_pred[i] = 0.f;
    if (i < 32 * 1024) { g_flagA[i] = 0; g_flagB[i] = 0; }
}

__global__ void setup_embWo(const float* __restrict__ emb, const float* __restrict__ Wo) {
    int o = threadIdx.x;
    float a = 0.f;
    for (int j = 0; j < 256; j++) a = fmaf(emb[o * 256 + j], Wo[j], a);
    g_embWo[o] = a;
}

// ---------------- K1: fused precompute GEMM (f32 in) ----------------
__global__ __launch_bounds__(256) void gemm_pre(
    const float* __restrict__ in, const float* __restrict__ Ua,
    const float* __restrict__ Uo, const float* __restrict__ Co,
    const float* __restrict__ Ba2, const float* __restrict__ Bo2,
    const float* __restrict__ Bo3, const float* __restrict__ Bo4,
    u16* __restrict__ E, float* __restrict__ outStage, u16* __restrict__ ic) {
    __shared__ __align__(16) float smA[32][132];
    __shared__ __align__(16) float smB[32][128];

    int tid = threadIdx.x;
    int rt = blockIdx.x, ct = blockIdx.y;
    int mat = ct >> 1;
    int o0 = (ct & 1) * 128;
    const float* W = (mat == 0) ? Ua : (mat == 1 ? Uo : Co);
    int r0 = rt * 128;
    int b = r0 >> 10, t0 = r0 & 1023;
    int tr = tid >> 4, tc = tid & 15;

    float acc[8][8];
#pragma unroll
    for (int i = 0; i < 8; i++)
#pragma unroll
        for (int j = 0; j < 8; j++) acc[i][j] = 0.f;

    for (int kc = 0; kc < 1024; kc += 32) {
#pragma unroll
        for (int l = 0; l < 4; l++) {
            int s = tid + l * 256;
            int i = s >> 3, c = s & 7;
            float4 v = *(const float4*)(in + (size_t)(r0 + i) * 1024 + kc + c * 4);
            smA[c * 4 + 0][i] = v.x;
            smA[c * 4 + 1][i] = v.y;
            smA[c * 4 + 2][i] = v.z;
            smA[c * 4 + 3][i] = v.w;
        }
#pragma unroll
        for (int l = 0; l < 4; l++) {
            int s = tid + l * 256;
            int dd = s >> 5, c = s & 31;
            *(float4*)&smB[dd][c * 4] = *(const float4*)(W + (size_t)(kc + dd) * 256 + o0 + c * 4);
        }
        __syncthreads();
#pragma unroll 4
        for (int j = 0; j < 32; j++) {
            float a0[8], b0[8];
            *(float4*)&a0[0] = *(const float4*)&smA[j][tr * 8];
            *(float4*)&a0[4] = *(const float4*)&smA[j][tr * 8 + 4];
            *(float4*)&b0[0] = *(const float4*)&smB[j][tc * 8];
            *(float4*)&b0[4] = *(const float4*)&smB[j][tc * 8 + 4];
#pragma unroll
            for (int rr = 0; rr < 8; rr++)
#pragma unroll
                for (int cc = 0; cc < 8; cc++) acc[rr][cc] = fmaf(a0[rr], b0[cc], acc[rr][cc]);
        }
        __syncthreads();
    }

    if (mat == 0) {
#pragma unroll
        for (int rr = 0; rr < 8; rr++) {
            int t = t0 + tr * 8 + rr;
#pragma unroll
            for (int cc = 0; cc < 8; cc++) {
                int o = o0 + tc * 8 + cc;
                float v = __expf(2.f * (acc[rr][cc] + Ba2[t * 256 + o]));
                E[((((size_t)b << 10) + t) << 8) + o] = f2b(v);   // [b][t][o]
            }
        }
    } else if (mat == 1) {
#pragma unroll
        for (int rr = 0; rr < 8; rr++) {
            int t = t0 + tr * 8 + rr;
            int t1 = (t + 1) & 1023;
#pragma unroll
            for (int cc = 0; cc < 8; cc++) {
                int o = o0 + tc * 8 + cc;
                outStage[(((size_t)b << 10) + t1) * 256 + o] = acc[rr][cc] + Bo2[o] + Bo3[o] + Bo4[o];
            }
        }
    } else {
#pragma unroll
        for (int rr = 0; rr < 8; rr++) {
            int t = t0 + tr * 8 + rr;
#pragma unroll
            for (int cc = 0; cc < 8; cc++)
                ic[(((size_t)b << 10) + t) * 256 + o0 + tc * 8 + cc] = f2b(acc[rr][cc]);
        }
    }
}

// ---------------- K2: scan, 8 blocks/b x 512 thr, fence-free atomics ----------
__global__ __launch_bounds__(NTH) void seq8(
    const float* __restrict__ Wa, const float* __restrict__ Va,
    const float* __restrict__ Ba1, const float* __restrict__ Ba3,
    const u16* __restrict__ E, const u16* __restrict__ IC,
    float* __restrict__ out) {
    __shared__ uint32 smWa2[128 * 256];     // 128 KB: Wa bf16-packed [j2][o]
    __shared__ float smVa[256], smBa1[256], smF[256], smQ[256], smBa3[128];
    __shared__ float smW[1024];             // WaS scratch (0..511) then weights
    __shared__ float smRed[33 * 32];        // phase-D partials, stride 33
    __shared__ float smT[16];

    int tid = threadIdx.x;
    int b = blockIdx.x & 31, g = blockIdx.x >> 5;
    int lane = tid & 63, w = tid >> 6;

    if (tid < 256) { smVa[tid] = Va[tid]; smBa1[tid] = Ba1[tid]; }
    if (tid < 128) smBa3[tid] = Ba3[(g << 7) + tid];
    // full Wa -> LDS, bf16-packed along j: smWa2[j2*256+o] = (Wa[2j2+1][o],Wa[2j2][o])
    for (int idx = tid; idx < 32768; idx += NTH) {
        int j2 = idx >> 8, o = idx & 255;
        uint32 u0 = (uint32)f2b(Wa[(size_t)(2 * j2) * 256 + o]);
        uint32 u1 = (uint32)f2b(Wa[(size_t)(2 * j2 + 1) * 256 + o]);
        smWa2[idx] = u0 | (u1 << 16);
    }
    __syncthreads();

    float sv = (tid < 256) ? smVa[tid] : 0.f;
#pragma unroll
    for (int off = 32; off; off >>= 1) sv += __shfl_xor(sv, off, 64);
    if (lane == 0) smT[w] = sv;
    __syncthreads();
    float sumVa = smT[0] + smT[1] + smT[2] + smT[3];
    float myEmb = (tid < 256) ? g_embWo[tid] : 0.f;
    __syncthreads();

    float* outb = out + ((size_t)b << 18);

    for (int t = 0; t < 1024; t++) {
        int fb = (b << 10) + t;
        // ---- wait pred(t-1) ready ----
        if (t > 0) {
            if (tid == 0) {
                int bud = 20000000;
                while (atomicAdd(&g_flagB[fb - 1], 0) < GG && --bud) {}
            }
            __syncthreads();
        }
        // ---- phase A (tid<256): read pred via TCC atomics; softmaxO pieces ----
        float pv = 0.f;
        if (tid < 256) {
            pv = atomicAdd(&g_pred[(b << 8) + tid], 0.f);
            float m = pv;
#pragma unroll
            for (int off = 32; off; off >>= 1) m = fmaxf(m, __shfl_xor(m, off, 64));
            if (lane == 0) smT[w] = m;
        }
        __syncthreads();
        if (tid < 256) {
            float M = fmaxf(fmaxf(smT[0], smT[1]), fmaxf(smT[2], smT[3]));
            float e = __expf(pv - M);
            float s1 = e, s2 = e * myEmb;
#pragma unroll
            for (int off = 32; off; off >>= 1) {
                s1 += __shfl_xor(s1, off, 64);
                s2 += __shfl_xor(s2, off, 64);
            }
            if (lane == 0) { smT[4 + w] = s1; smT[8 + w] = s2; }
            smQ[tid] = tanh_fast(pv);
        }
        __syncthreads();
        // ---- WaS (all 512): full 256x256 GEMV from LDS Wa ----
        {
            int o = tid & 255, h = tid >> 8;
            float a = 0.f;
            const uint32* wp = &smWa2[(h << 6) * 256 + o];
            const float* qp = &smQ[h << 7];
#pragma unroll 8
            for (int j2 = 0; j2 < 64; j2++) {
                float2 q2 = *(const float2*)&qp[j2 * 2];
                uint32 p = wp[j2 << 8];
                a = fmaf(lo_bf(p), q2.x, a);
                a = fmaf(hi_bf(p), q2.y, a);
            }
            smW[tid] = a;
        }
        float p_val = (smT[8] + smT[9] + smT[10] + smT[11]) *
                      __builtin_amdgcn_rcpf(smT[4] + smT[5] + smT[6] + smT[7]);
        __syncthreads();
        if (tid < 256) smF[tid] = __expf(2.f * (smBa1[tid] + smW[tid] + smW[256 + tid]));
        __syncthreads();

        // ---- phase C: scores for t' slice [128g,128g+128), 4 thr/row ----
        {
            int tl = tid >> 2, oq = tid & 3;
            int tp = (g << 7) + tl;
            const uint4* row = (const uint4*)(E + ((((size_t)b << 10) + tp) << 8) + (oq << 6));
            float acc = 0.f;
#pragma unroll
            for (int k = 0; k < 8; k++) {
                uint4 ev = row[k];
                int ob = (oq << 6) + (k << 3);
                float4 fA = *(const float4*)&smF[ob];
                float4 fB = *(const float4*)&smF[ob + 4];
                float4 vA = *(const float4*)&smVa[ob];
                float4 vB = *(const float4*)&smVa[ob + 4];
                acc = fmaf(vA.x, __builtin_amdgcn_rcpf(fmaf(lo_bf(ev.x), fA.x, 1.f)), acc);
                acc = fmaf(vA.y, __builtin_amdgcn_rcpf(fmaf(hi_bf(ev.x), fA.y, 1.f)), acc);
                acc = fmaf(vA.z, __builtin_amdgcn_rcpf(fmaf(lo_bf(ev.y), fA.z, 1.f)), acc);
                acc = fmaf(vA.w, __builtin_amdgcn_rcpf(fmaf(hi_bf(ev.y), fA.w, 1.f)), acc);
                acc = fmaf(vB.x, __builtin_amdgcn_rcpf(fmaf(lo_bf(ev.z), fB.x, 1.f)), acc);
                acc = fmaf(vB.y, __builtin_amdgcn_rcpf(fmaf(hi_bf(ev.z), fB.y, 1.f)), acc);
                acc = fmaf(vB.z, __builtin_amdgcn_rcpf(fmaf(lo_bf(ev.w), fB.z, 1.f)), acc);
                acc = fmaf(vB.w, __builtin_amdgcn_rcpf(fmaf(hi_bf(ev.w), fB.w, 1.f)), acc);
            }
            acc += __shfl_xor(acc, 1, 64);
            acc += __shfl_xor(acc, 2, 64);
            if (oq == 0)
                atomicExch(&g_scores[(b << 10) + tp], sumVa - 2.f * acc + smBa3[tl]);
        }
        __threadfence_block();   // waitcnt drain only; no cache ops
        __syncthreads();
        if (tid == 0) {
            atomicAdd(&g_flagA[fb], 1);
            int bud = 20000000;
            while (atomicAdd(&g_flagA[fb], 0) < GG && --bud) {}
        }
        __syncthreads();

        // ---- softmax over all 1024 scores (redundant per block, TCC reads) ----
        float s0 = atomicAdd(&g_scores[(b << 10) + tid], 0.f);
        float s1_ = atomicAdd(&g_scores[(b << 10) + 512 + tid], 0.f);
        float mm = fmaxf(s0, s1_);
#pragma unroll
        for (int off = 32; off; off >>= 1) mm = fmaxf(mm, __shfl_xor(mm, off, 64));
        if (lane == 0) smT[w] = mm;
        __syncthreads();
        float M2 = smT[0];
#pragma unroll
        for (int i = 1; i < 8; i++) M2 = fmaxf(M2, smT[i]);
        float e0 = __expf(s0 - M2), e1 = __expf(s1_ - M2);
        smW[tid] = e0;
        smW[512 + tid] = e1;
        float ls = e0 + e1;
#pragma unroll
        for (int off = 32; off; off >>= 1) ls += __shfl_xor(ls, off, 64);
        if (lane == 0) smT[8 + w] = ls;
        __syncthreads();
        float L = 0.f;
#pragma unroll
        for (int i = 0; i < 8; i++) L += smT[8 + i];
        float invL = __builtin_amdgcn_rcpf(L);

        // ---- phase D: o-chunk [32g,32g+32), sum over all t' (plain IC loads) --
        {
            int tc = tid >> 4, op = (tid & 15) << 1;
            const u16* icp = IC + ((((size_t)b << 10) + (tc << 5)) << 8) + (g << 5) + op;
            float a0 = 0.f, a1 = 0.f;
#pragma unroll 8
            for (int i = 0; i < 32; i++) {
                uint32 iv = *(const uint32*)(icp + ((size_t)i << 8));
                float wv = smW[(tc << 5) + i];
                a0 = fmaf(wv, lo_bf(iv), a0);
                a1 = fmaf(wv, hi_bf(iv), a1);
            }
            smRed[tc * 33 + op] = a0;
            smRed[tc * 33 + op + 1] = a1;
        }
        __syncthreads();
        if (tid < 32) {
            float s = 0.f;
#pragma unroll
            for (int c = 0; c < 32; c++) s += smRed[c * 33 + tid];
            float uoh = outb[((size_t)t << 8) + (g << 5) + tid];
            float pr = p_val + uoh + invL * s;
            outb[((size_t)t << 8) + (g << 5) + tid] = pr;
            atomicExch(&g_pred[(b << 8) + (g << 5) + tid], pr);
        }
        __threadfence_block();
        __syncthreads();
        if (tid == 0) atomicAdd(&g_flagB[fb], 1);
    }
}

// ---------------- fallback (ws too small): diagnostic zero-fill ----------------
__global__ void zero_k(uint32* out, int n) {
    int i = blockIdx.x * 1024 + threadIdx.x;
    if (i < n) out[i] = 0;
}

extern "C" void kernel_launch(void* const* d_in, const int* in_sizes, int n_in,
                              void* d_out, int out_size, void* d_ws, size_t ws_size,
                              hipStream_t stream) {
    const float* in = (const float*)d_in[0];
    const float* Wa = (const float*)d_in[1];
    const float* Ua = (const float*)d_in[2];
    const float* Va = (const float*)d_in[3];
    const float* Ba1 = (const float*)d_in[4];
    const float* Ba2 = (const float*)d_in[5];
    const float* Ba3 = (const float*)d_in[6];
    const float* Wo = (const float*)d_in[7];
    const float* Uo = (const float*)d_in[8];
    const float* Co = (const float*)d_in[9];
    const float* Bo2 = (const float*)d_in[10];
    const float* Bo3 = (const float*)d_in[11];
    const float* Bo4 = (const float*)d_in[12];
    const float* emb = (const float*)d_in[13];
    float* out = (float*)d_out;
    char* ws = (char*)d_ws;

    if (ws_size < WS_NEEDED) {
        zero_k<<<(out_size + 1023) / 1024, 1024, 0, stream>>>((uint32*)out, out_size);
        return;
    }

    u16* E = (u16*)(ws + OFF_E);
    u16* icp = (u16*)(ws + OFF_IC);

    init_k<<<256, 256, 0, stream>>>();
    setup_embWo<<<1, 256, 0, stream>>>(emb, Wo);
    gemm_pre<<<dim3(256, 6), 256, 0, stream>>>(in, Ua, Uo, Co, Ba2, Bo2, Bo3, Bo4, E, out, icp);
    seq8<<<256, NTH, 0, stream>>>(Wa, Va, Ba1, Ba3, E, icp, out);
}

// Round 7
// 7869.607 us; speedup vs baseline: 10.2976x; 1.3471x over previous
//
#include <hip/hip_runtime.h>
#include <hip/hip_fp16.h>

// CascadedAttention: B=32, T=1024, D=1024, O=256. All I/O f32.
// ws (33.55 MB): E[b][t][o]=exp(2*(in@Ua+Ba2)) bf16; IC[b][t][o]=in@Co bf16.
// UoHp staged in d_out (f32), read at step t before the step's publish,
// overwritten by pred only after the step-t exchange completes.
// Scan: 256 blocks x 512 thr; b=blk&31, g=blk>>5. ONE exchange per step:
// block g publishes (m_g, S_g, P_g[256]) of its 128-t' slice as
// (t<<16|f16) tagged words (atomicExch); all blocks poll tags (atomicAdd+0),
// merge online-softmax style, and rebuild the FULL pred locally. No flags,
// no fences, parity double-buffer on t&1.
// R7 fix: poll caches init to tag 0xFFFF (R6 init of 0 matched t=0 and
// skipped the read entirely -> L=0 -> rcp(0)*0 = NaN).

typedef unsigned int uint32;
typedef unsigned short u16;

#define NTH 512

__device__ __forceinline__ float b2f(u16 u) { return __uint_as_float(((uint32)u) << 16); }
__device__ __forceinline__ u16 f2b(float f) {
    uint32 u = __float_as_uint(f);
    uint32 r = u + 0x7fffu + ((u >> 16) & 1u);
    return (u16)(r >> 16);
}
__device__ __forceinline__ float lo_bf(uint32 d) { return __uint_as_float(d << 16); }
__device__ __forceinline__ float hi_bf(uint32 d) { return __uint_as_float(d & 0xffff0000u); }
__device__ __forceinline__ float tanh_fast(float x) {
    float e = __expf(x + x);
    return 1.0f - 2.0f * __builtin_amdgcn_rcpf(e + 1.0f);
}
__device__ __forceinline__ uint32 packh(float f, int t) {
    return (((uint32)t) << 16) | (uint32)__half_as_ushort(__float2half(f));
}
__device__ __forceinline__ float unpackh(uint32 w) {
    return __half2float(__ushort_as_half((unsigned short)(w & 0xFFFFu)));
}

#define OFF_E  ((size_t)0)
#define OFF_IC ((size_t)16777216)
#define WS_NEEDED ((size_t)33554432)

// exchange: [parity][b][g*258 + k], k<256 = P_g[o], 256 = m_g, 257 = S_g
__device__ uint32 g_P[2][32][2064];
__device__ float g_embWo[256];

__global__ __launch_bounds__(256) void init_k() {
    int i = blockIdx.x * 256 + threadIdx.x;       // grid 516 -> 132096
    ((uint32*)g_P)[i] = 0xFFFF0000u;
}

__global__ void setup_embWo(const float* __restrict__ emb, const float* __restrict__ Wo) {
    int o = threadIdx.x;
    float a = 0.f;
    for (int j = 0; j < 256; j++) a = fmaf(emb[o * 256 + j], Wo[j], a);
    g_embWo[o] = a;
}

// ---------------- K1: fused precompute GEMM (f32 in) ----------------
__global__ __launch_bounds__(256) void gemm_pre(
    const float* __restrict__ in, const float* __restrict__ Ua,
    const float* __restrict__ Uo, const float* __restrict__ Co,
    const float* __restrict__ Ba2, const float* __restrict__ Bo2,
    const float* __restrict__ Bo3, const float* __restrict__ Bo4,
    u16* __restrict__ E, float* __restrict__ outStage, u16* __restrict__ ic) {
    __shared__ __align__(16) float smA[32][132];
    __shared__ __align__(16) float smB[32][128];

    int tid = threadIdx.x;
    int rt = blockIdx.x, ct = blockIdx.y;
    int mat = ct >> 1;
    int o0 = (ct & 1) * 128;
    const float* W = (mat == 0) ? Ua : (mat == 1 ? Uo : Co);
    int r0 = rt * 128;
    int b = r0 >> 10, t0 = r0 & 1023;
    int tr = tid >> 4, tc = tid & 15;

    float acc[8][8];
#pragma unroll
    for (int i = 0; i < 8; i++)
#pragma unroll
        for (int j = 0; j < 8; j++) acc[i][j] = 0.f;

    for (int kc = 0; kc < 1024; kc += 32) {
#pragma unroll
        for (int l = 0; l < 4; l++) {
            int s = tid + l * 256;
            int i = s >> 3, c = s & 7;
            float4 v = *(const float4*)(in + (size_t)(r0 + i) * 1024 + kc + c * 4);
            smA[c * 4 + 0][i] = v.x;
            smA[c * 4 + 1][i] = v.y;
            smA[c * 4 + 2][i] = v.z;
            smA[c * 4 + 3][i] = v.w;
        }
#pragma unroll
        for (int l = 0; l < 4; l++) {
            int s = tid + l * 256;
            int dd = s >> 5, c = s & 31;
            *(float4*)&smB[dd][c * 4] = *(const float4*)(W + (size_t)(kc + dd) * 256 + o0 + c * 4);
        }
        __syncthreads();
#pragma unroll 4
        for (int j = 0; j < 32; j++) {
            float a0[8], b0[8];
            *(float4*)&a0[0] = *(const float4*)&smA[j][tr * 8];
            *(float4*)&a0[4] = *(const float4*)&smA[j][tr * 8 + 4];
            *(float4*)&b0[0] = *(const float4*)&smB[j][tc * 8];
            *(float4*)&b0[4] = *(const float4*)&smB[j][tc * 8 + 4];
#pragma unroll
            for (int rr = 0; rr < 8; rr++)
#pragma unroll
                for (int cc = 0; cc < 8; cc++) acc[rr][cc] = fmaf(a0[rr], b0[cc], acc[rr][cc]);
        }
        __syncthreads();
    }

    if (mat == 0) {
#pragma unroll
        for (int rr = 0; rr < 8; rr++) {
            int t = t0 + tr * 8 + rr;
#pragma unroll
            for (int cc = 0; cc < 8; cc++) {
                int o = o0 + tc * 8 + cc;
                float v = __expf(2.f * (acc[rr][cc] + Ba2[t * 256 + o]));
                E[((((size_t)b << 10) + t) << 8) + o] = f2b(v);   // [b][t][o]
            }
        }
    } else if (mat == 1) {
#pragma unroll
        for (int rr = 0; rr < 8; rr++) {
            int t = t0 + tr * 8 + rr;
            int t1 = (t + 1) & 1023;
#pragma unroll
            for (int cc = 0; cc < 8; cc++) {
                int o = o0 + tc * 8 + cc;
                outStage[(((size_t)b << 10) + t1) * 256 + o] = acc[rr][cc] + Bo2[o] + Bo3[o] + Bo4[o];
            }
        }
    } else {
#pragma unroll
        for (int rr = 0; rr < 8; rr++) {
            int t = t0 + tr * 8 + rr;
#pragma unroll
            for (int cc = 0; cc < 8; cc++)
                ic[(((size_t)b << 10) + t) * 256 + o0 + tc * 8 + cc] = f2b(acc[rr][cc]);
        }
    }
}

// ---------------- K2: scan, 8 blocks/b x 512 thr, single exchange/step --------
__global__ __launch_bounds__(NTH) void seq8(
    const float* __restrict__ Wa, const float* __restrict__ Va,
    const float* __restrict__ Ba1, const float* __restrict__ Ba3,
    const u16* __restrict__ E, const u16* __restrict__ IC,
    float* __restrict__ out) {
    __shared__ uint32 smWa2[128 * 256];     // 128 KB bf16-packed Wa
    __shared__ __align__(16) float smScratch[2064];
    __shared__ float smPred[256], smQ[256], smF[256], smVa[256], smBa1[256];
    __shared__ float smS[128], smEe[128], smBa3[128];
    __shared__ float smT[16];

    int tid = threadIdx.x;
    int b = blockIdx.x & 31, g = blockIdx.x >> 5;
    int lane = tid & 63, w = tid >> 6;
    int t0 = g << 7;

    if (tid < 256) {
        smVa[tid] = Va[tid]; smBa1[tid] = Ba1[tid];
        smPred[tid] = 0.f; smQ[tid] = 0.f;
    }
    if (tid < 128) smBa3[tid] = Ba3[t0 + tid];
    for (int idx = tid; idx < 32768; idx += NTH) {
        int j2 = idx >> 8, o = idx & 255;
        uint32 u0 = (uint32)f2b(Wa[(size_t)(2 * j2) * 256 + o]);
        uint32 u1 = (uint32)f2b(Wa[(size_t)(2 * j2 + 1) * 256 + o]);
        smWa2[idx] = u0 | (u1 << 16);
    }
    __syncthreads();

    float sv = (tid < 256) ? smVa[tid] : 0.f;
#pragma unroll
    for (int off = 32; off; off >>= 1) sv += __shfl_xor(sv, off, 64);
    if (lane == 0) smT[w] = sv;
    __syncthreads();
    float sumVa = smT[0] + smT[1] + smT[2] + smT[3];
    float myEmb = (tid < 256) ? g_embWo[tid] : 0.f;
    __syncthreads();

    const u16* Eb = E + ((size_t)b << 18);
    const u16* ICb = IC + ((size_t)b << 18);
    float* outb = out + ((size_t)b << 18);
    long bud = 1000000000L;   // hang guard

    for (int t = 0; t < 1024; t++) {
        uint32* buf = &g_P[t & 1][b][0];
        // UoHp row read — precedes publish (ordering: read -> our publish ->
        // others' poll-pass -> others' write of this row)
        float uoh = (tid < 256) ? outb[((size_t)t << 8) + tid] : 0.f;

        // ---- phase A partials (tid<256) + WaS GEMV (all 512) ----
        float pv = 0.f;
        if (tid < 256) {
            pv = smPred[tid];
            float m = pv;
#pragma unroll
            for (int off = 32; off; off >>= 1) m = fmaxf(m, __shfl_xor(m, off, 64));
            if (lane == 0) smT[w] = m;
        }
        {
            int o = tid & 255, h = tid >> 8;
            const uint32* wp = &smWa2[(h << 6) * 256 + o];
            const float* qp = &smQ[h << 7];
            float a = 0.f;
#pragma unroll 8
            for (int j2 = 0; j2 < 64; j2++) {
                float2 q2 = *(const float2*)&qp[j2 * 2];
                uint32 p = wp[j2 << 8];
                a = fmaf(lo_bf(p), q2.x, a);
                a = fmaf(hi_bf(p), q2.y, a);
            }
            smScratch[tid] = a;
        }
        __syncthreads();   // S1
        if (tid < 256) {
            float M = fmaxf(fmaxf(smT[0], smT[1]), fmaxf(smT[2], smT[3]));
            float e = __expf(pv - M);
            float s1 = e, s2 = e * myEmb;
#pragma unroll
            for (int off = 32; off; off >>= 1) {
                s1 += __shfl_xor(s1, off, 64);
                s2 += __shfl_xor(s2, off, 64);
            }
            if (lane == 0) { smT[4 + w] = s1; smT[8 + w] = s2; }
            smF[tid] = __expf(2.f * (smBa1[tid] + smScratch[tid] + smScratch[256 + tid]));
        }
        __syncthreads();   // S2
        float p_val = (smT[8] + smT[9] + smT[10] + smT[11]) *
                      __builtin_amdgcn_rcpf(smT[4] + smT[5] + smT[6] + smT[7]);

        // ---- phase C: scores for own 128-t' slice, 4 thr/row ----
        {
            int tl = tid >> 2, oq = tid & 3;
            const uint4* row = (const uint4*)(Eb + (((size_t)(t0 + tl)) << 8) + (oq << 6));
            float acc = 0.f;
#pragma unroll
            for (int k = 0; k < 8; k++) {
                uint4 ev = row[k];
                int ob = (oq << 6) + (k << 3);
                float4 fA = *(const float4*)&smF[ob];
                float4 fB = *(const float4*)&smF[ob + 4];
                float4 vA = *(const float4*)&smVa[ob];
                float4 vB = *(const float4*)&smVa[ob + 4];
                acc = fmaf(vA.x, __builtin_amdgcn_rcpf(fmaf(lo_bf(ev.x), fA.x, 1.f)), acc);
                acc = fmaf(vA.y, __builtin_amdgcn_rcpf(fmaf(hi_bf(ev.x), fA.y, 1.f)), acc);
                acc = fmaf(vA.z, __builtin_amdgcn_rcpf(fmaf(lo_bf(ev.y), fA.z, 1.f)), acc);
                acc = fmaf(vA.w, __builtin_amdgcn_rcpf(fmaf(hi_bf(ev.y), fA.w, 1.f)), acc);
                acc = fmaf(vB.x, __builtin_amdgcn_rcpf(fmaf(lo_bf(ev.z), fB.x, 1.f)), acc);
                acc = fmaf(vB.y, __builtin_amdgcn_rcpf(fmaf(hi_bf(ev.z), fB.y, 1.f)), acc);
                acc = fmaf(vB.z, __builtin_amdgcn_rcpf(fmaf(lo_bf(ev.w), fB.z, 1.f)), acc);
                acc = fmaf(vB.w, __builtin_amdgcn_rcpf(fmaf(hi_bf(ev.w), fB.w, 1.f)), acc);
            }
            acc += __shfl_xor(acc, 1, 64);
            acc += __shfl_xor(acc, 2, 64);
            if (oq == 0) smS[tl] = sumVa - 2.f * acc + smBa3[tl];
        }
        __syncthreads();   // S3
        // ---- local softmax stats over 128 scores ----
        float m_g = 0.f, S_g = 0.f;
        if (tid < 128) {
            float s = smS[tid];
            float mm = s;
#pragma unroll
            for (int off = 32; off; off >>= 1) mm = fmaxf(mm, __shfl_xor(mm, off, 64));
            if (lane == 0) smT[w] = mm;
        }
        __syncthreads();   // S4
        if (tid < 128) {
            m_g = fmaxf(smT[0], smT[1]);
            float e = __expf(smS[tid] - m_g);
            smEe[tid] = e;
            float ls = e;
#pragma unroll
            for (int off = 32; off; off >>= 1) ls += __shfl_xor(ls, off, 64);
            if (lane == 0) smT[2 + w] = ls;
        }
        __syncthreads();   // S5
        m_g = fmaxf(smT[0], smT[1]);
        S_g = smT[2] + smT[3];

        // ---- P_g partial: e-weighted IC rows of own slice ----
        {
            int rg = tid >> 6, oc = tid & 63, o4 = oc << 2;
            const u16* icp = ICb + (((size_t)t0) << 8) + o4;
            float4 a4 = {0.f, 0.f, 0.f, 0.f};
#pragma unroll 4
            for (int r = 0; r < 16; r++) {
                int row = (rg << 4) + r;
                float e = smEe[row];
                uint2 iv = *(const uint2*)(icp + ((size_t)row << 8));
                a4.x = fmaf(e, lo_bf(iv.x), a4.x);
                a4.y = fmaf(e, hi_bf(iv.x), a4.y);
                a4.z = fmaf(e, lo_bf(iv.y), a4.z);
                a4.w = fmaf(e, hi_bf(iv.y), a4.w);
            }
            *(float4*)&smScratch[rg * 256 + o4] = a4;
        }
        __syncthreads();   // S6
        // ---- publish 258 tagged words ----
        if (tid < 256) {
            float P = 0.f;
#pragma unroll
            for (int rg = 0; rg < 8; rg++) P += smScratch[rg * 256 + tid];
            atomicExch(&buf[g * 258 + tid], packh(P, t));
        }
        if (tid == 0) {
            atomicExch(&buf[g * 258 + 256], packh(m_g, t));
            atomicExch(&buf[g * 258 + 257], packh(S_g, t));
        }
        __syncthreads();   // S7 (smScratch reads done before poll overwrites)
        // ---- poll all 2064 words, overlapped RTs ----
        {
            uint32 tt = (uint32)t;
            // R7 FIX: init caches with tag 0xFFFF (never equals t) so every
            // word is actually read at least once each step.
            uint32 w0 = 0xFFFF0000u, w1 = 0xFFFF0000u, w2 = 0xFFFF0000u, w3 = 0xFFFF0000u;
            int has4 = (tid < 16);
            uint32 w4 = has4 ? 0xFFFF0000u : (tt << 16);
            while (bud > 0) {
                if ((w0 >> 16) != tt) w0 = atomicAdd(&buf[tid], 0u);
                if ((w1 >> 16) != tt) w1 = atomicAdd(&buf[tid + 512], 0u);
                if ((w2 >> 16) != tt) w2 = atomicAdd(&buf[tid + 1024], 0u);
                if ((w3 >> 16) != tt) w3 = atomicAdd(&buf[tid + 1536], 0u);
                if (has4 && (w4 >> 16) != tt) w4 = atomicAdd(&buf[tid + 2048], 0u);
                if ((w0 >> 16) == tt && (w1 >> 16) == tt && (w2 >> 16) == tt &&
                    (w3 >> 16) == tt && (w4 >> 16) == tt) break;
                bud--;
            }
            smScratch[tid] = unpackh(w0);
            smScratch[tid + 512] = unpackh(w1);
            smScratch[tid + 1024] = unpackh(w2);
            smScratch[tid + 1536] = unpackh(w3);
            if (has4) smScratch[tid + 2048] = unpackh(w4);
        }
        __syncthreads();   // S8
        // ---- merge + full pred rebuild (tid<256) ----
        if (tid < 256) {
            float M = smScratch[256];
#pragma unroll
            for (int g2 = 1; g2 < 8; g2++) M = fmaxf(M, smScratch[g2 * 258 + 256]);
            float L = 0.f, Pt = 0.f;
#pragma unroll
            for (int g2 = 0; g2 < 8; g2++) {
                float eg = __expf(smScratch[g2 * 258 + 256] - M);
                L = fmaf(eg, smScratch[g2 * 258 + 257], L);
                Pt = fmaf(eg, smScratch[g2 * 258 + tid], Pt);
            }
            float pr = p_val + uoh + Pt * __builtin_amdgcn_rcpf(L);
            if ((tid >> 5) == g) outb[((size_t)t << 8) + tid] = pr;
            smPred[tid] = pr;
            smQ[tid] = tanh_fast(pr);
        }
        __syncthreads();   // S9
    }
}

// ---------------- fallback (ws too small): diagnostic zero-fill ----------------
__global__ void zero_k(uint32* out, int n) {
    int i = blockIdx.x * 1024 + threadIdx.x;
    if (i < n) out[i] = 0;
}

extern "C" void kernel_launch(void* const* d_in, const int* in_sizes, int n_in,
                              void* d_out, int out_size, void* d_ws, size_t ws_size,
                              hipStream_t stream) {
    const float* in = (const float*)d_in[0];
    const float* Wa = (const float*)d_in[1];
    const float* Ua = (const float*)d_in[2];
    const float* Va = (const float*)d_in[3];
    const float* Ba1 = (const float*)d_in[4];
    const float* Ba2 = (const float*)d_in[5];
    const float* Ba3 = (const float*)d_in[6];
    const float* Wo = (const float*)d_in[7];
    const float* Uo = (const float*)d_in[8];
    const float* Co = (const float*)d_in[9];
    const float* Bo2 = (const float*)d_in[10];
    const float* Bo3 = (const float*)d_in[11];
    const float* Bo4 = (const float*)d_in[12];
    const float* emb = (const float*)d_in[13];
    float* out = (float*)d_out;
    char* ws = (char*)d_ws;

    if (ws_size < WS_NEEDED) {
        zero_k<<<(out_size + 1023) / 1024, 1024, 0, stream>>>((uint32*)out, out_size);
        return;
    }

    u16* E = (u16*)(ws + OFF_E);
    u16* icp = (u16*)(ws + OFF_IC);

    init_k<<<516, 256, 0, stream>>>();
    setup_embWo<<<1, 256, 0, stream>>>(emb, Wo);
    gemm_pre<<<dim3(256, 6), 256, 0, stream>>>(in, Ua, Uo, Co, Ba2, Bo2, Bo3, Bo4, E, out, icp);
    seq8<<<256, NTH, 0, stream>>>(Wa, Va, Ba1, Ba3, E, icp, out);
}